// Round 5
// baseline (871.247 us; speedup 1.0000x reference)
//
#include <hip/hip_runtime.h>
#include <hip/hip_bf16.h>
#include <math.h>

#define NND 50000
#define NE  600000
#define HD  128
#define NC  10
#define CAP 64          // per-node in-edge bucket capacity (Poisson mean 12; P(>=64) ~ 1e-30)
#define GEMMB 782       // gemm blocks in k_mega (782*64 = 50048 rows)
#define ATOMB 1024      // atomic blocks in k_mega

typedef unsigned short ushort_t;
typedef __attribute__((ext_vector_type(8))) short short8;
typedef __attribute__((ext_vector_type(4))) float f32x4;

__device__ __forceinline__ float bf2f(unsigned short u) {
  return __uint_as_float(((unsigned int)u) << 16);
}
__device__ __forceinline__ unsigned short f2bf(float f) {
  __hip_bfloat16 h = __float2bfloat16(f);  // RNE
  return *(unsigned short*)&h;
}

// ---------------- init (pos=0, rowcnt=0, loss=0) + weight fragment prep ----------------
// blocks [0,196): zero arrays; blocks [196,213): pack Wfc/W1/W2 into MFMA B-fragment order.
// B-frag layout (HW-verified R3/R4): Bfrag[(t*64+lane)*8+j] = W[n = nt*16 + (lane&15)][k = t*32 + ((lane>>4)&3)*8 + j]
__global__ void k_init_prep(int* pos, int* rowcnt, float* lossb,
                            const float* __restrict__ Wfc, const float* __restrict__ W1,
                            const float* __restrict__ W2, ushort_t* __restrict__ Bp,
                            ushort_t* __restrict__ Bw1, ushort_t* __restrict__ Bw2) {
  int bb = blockIdx.x, tid = threadIdx.x;
  if (bb < 196) {
    int i = bb * 256 + tid;
    if (i < NND) { pos[i] = 0; rowcnt[i] = 0; }
    if (bb == 0 && tid == 0) lossb[0] = 0.0f;
  } else if (bb == 196) {
    // Wfc: K=256, one 16-padded n-tile
    for (int idx = tid; idx < 8 * 64; idx += 256) {
      int t = idx >> 6, lane = idx & 63;
      int n = lane & 15, q = (lane >> 4) & 3;
      #pragma unroll
      for (int j = 0; j < 8; j++) {
        int k = t * 32 + q * 8 + j;
        float v = (n < NC) ? Wfc[n * 256 + k] : 0.f;
        Bp[idx * 8 + j] = f2bf(v);
      }
    }
  } else {
    const float* W = (bb <= 204) ? W1 : W2;
    ushort_t* B = (bb <= 204) ? Bw1 : Bw2;
    int nt = (bb - 197) & 7;
    for (int idx = tid; idx < 4 * 64; idx += 256) {
      int t = idx >> 6, lane = idx & 63;
      int n = nt * 16 + (lane & 15), q = (lane >> 4) & 3;
      #pragma unroll
      for (int j = 0; j < 8; j++) {
        int k = t * 32 + q * 8 + j;
        B[(nt * 256 + idx) * 8 + j] = f2bf(W[n * HD + k]);
      }
    }
  }
}

// ---------------- shared GEMM body: Y[r][n] = b[n] + sum_k X[r][k]*W[n][k]; 64 rows/block ----------------
template <bool FP32IN>
__device__ __forceinline__ void gemm_body(const void* __restrict__ Xv,
                                          const ushort_t* __restrict__ Bw,
                                          const float* __restrict__ b,
                                          ushort_t* __restrict__ Y,
                                          ushort_t* Bs, int bid, int tid) {
  for (int i = tid; i < 2048; i += 256)
    *(short8*)&Bs[i * 8] = *(const short8*)&Bw[i * 8];
  __syncthreads();
  int w = tid >> 6, lane = tid & 63;
  int m = lane & 15, q = lane >> 4;
  int rowbase = bid * 64 + w * 16;
  int rm = rowbase + m; if (rm >= NND) rm = NND - 1;  // clamp: row m only affects row m outputs
  short8 a[4];
  if (FP32IN) {
    const float* X = (const float*)Xv;
    #pragma unroll
    for (int t = 0; t < 4; t++) {
      const float* p0 = &X[(long)rm * HD + t * 32 + q * 8];
      float4 x0 = *(const float4*)p0;
      float4 x1 = *(const float4*)(p0 + 4);
      short8 av;
      av[0] = (short)f2bf(x0.x); av[1] = (short)f2bf(x0.y);
      av[2] = (short)f2bf(x0.z); av[3] = (short)f2bf(x0.w);
      av[4] = (short)f2bf(x1.x); av[5] = (short)f2bf(x1.y);
      av[6] = (short)f2bf(x1.z); av[7] = (short)f2bf(x1.w);
      a[t] = av;
    }
  } else {
    const ushort_t* X = (const ushort_t*)Xv;
    #pragma unroll
    for (int t = 0; t < 4; t++)
      a[t] = *(const short8*)&X[(long)rm * HD + t * 32 + q * 8];
  }
  #pragma unroll
  for (int nt = 0; nt < 8; nt++) {
    f32x4 acc = {0.f, 0.f, 0.f, 0.f};
    #pragma unroll
    for (int t = 0; t < 4; t++) {
      short8 bf = *(const short8*)&Bs[((nt * 4 + t) * 64 + lane) * 8];
      acc = __builtin_amdgcn_mfma_f32_16x16x32_bf16(a[t], bf, acc, 0, 0, 0);
    }
    float bias = b[nt * 16 + m];
    #pragma unroll
    for (int reg = 0; reg < 4; reg++) {
      int r = rowbase + q * 4 + reg;
      if (r < NND) Y[(long)r * HD + nt * 16 + m] = f2bf(acc[reg] + bias);
    }
  }
}

// ---------------- mega: blocks [0,GEMMB) = conv1 GEMM; rest = graph build (atomics) ----------------
__global__ __launch_bounds__(256) void k_mega(const float* __restrict__ features,
                                              const ushort_t* __restrict__ Bw1,
                                              const float* __restrict__ b1,
                                              ushort_t* __restrict__ Y,
                                              const int* __restrict__ row,
                                              const int* __restrict__ col,
                                              int* pos, int* rowcnt,
                                              int* __restrict__ srcs) {
  __shared__ ushort_t Bs[16384];  // 32 KB (only gemm blocks touch it)
  int tid = threadIdx.x;
  if (blockIdx.x < GEMMB) {
    gemm_body<true>((const void*)features, Bw1, b1, Y, Bs, blockIdx.x, tid);
  } else {
    int idx = (blockIdx.x - GEMMB) * 256 + tid;
    for (int e = idx; e < NE; e += ATOMB * 256) {
      int c = col[e], r = row[e];
      int p = atomicAdd(&pos[c], 1);     // fill slot == running count
      if (p < CAP) srcs[(long)c * CAP + p] = r;
      atomicAdd(&rowcnt[r], 1);          // out-degree histogram
    }
  }
}

// ---------------- conv2 GEMM (bf16 in) ----------------
__global__ __launch_bounds__(256) void k_gemm2(const ushort_t* __restrict__ X,
                                               const ushort_t* __restrict__ Bw,
                                               const float* __restrict__ b,
                                               ushort_t* __restrict__ Y) {
  __shared__ ushort_t Bs[16384];
  gemm_body<false>((const void*)X, Bw, b, Y, Bs, blockIdx.x, threadIdx.x);
}

// ---------------- aggregation: padded buckets, 16B gathers, two neighbors in flight ----------------
// O[i] = dinv[i]^2*H[i] + sum_{e:col=i} dinv[src]*dinv[i]*H[src],  dinv = rsqrt(1+rowcnt)
__global__ __launch_bounds__(256) void k_aggr(const ushort_t* __restrict__ H,
                                              const int* __restrict__ srcs,
                                              const int* __restrict__ pos,
                                              const int* __restrict__ rowcnt,
                                              ushort_t* __restrict__ O) {
  int g = threadIdx.x >> 5, lane = threadIdx.x & 31;
  int half = lane >> 4;            // 0: even neighbor slots, 1: odd slots
  int fl = (lane & 15) * 8;        // feature base (8 bf16 = 16 B per lane)
  int node = blockIdx.x * 8 + g;
  if (node >= NND) return;
  float di = rsqrtf(1.0f + (float)rowcnt[node]);
  short8 hv = *(const short8*)&H[(long)node * HD + fl];
  float acc[8];
  float sw = (half == 0) ? di * di : 0.0f;   // self-loop term only in half 0
  #pragma unroll
  for (int j = 0; j < 8; j++) acc[j] = sw * bf2f((unsigned short)hv[j]);
  int cnt = pos[node]; if (cnt > CAP) cnt = CAP;
  const int* nb = &srcs[(long)node * CAP];
  for (int base = 0; base < cnt; base += 32) {
    int m = cnt - base; if (m > 32) m = 32;
    int sl = 0; float wl = 0.f;
    if (lane < m) { sl = nb[base + lane]; wl = di * rsqrtf(1.0f + (float)rowcnt[sl]); }
    int iters = (m + 1) >> 1;
    for (int u = 0; u < iters; u++) {
      int t = 2 * u + half;                      // t<=m; lane t>=m holds sl=0, wl=0
      int s = __shfl(sl, t & 31, 32);
      float w = __shfl(wl, t & 31, 32);
      short8 hs = *(const short8*)&H[(long)s * HD + fl];
      #pragma unroll
      for (int j = 0; j < 8; j++) acc[j] += w * bf2f((unsigned short)hs[j]);
    }
  }
  // combine halves: lanes 0-15 add lanes 16-31's partials
  #pragma unroll
  for (int j = 0; j < 8; j++) acc[j] += __shfl(acc[j], (lane & 15) + 16, 32);
  if (half == 0) {
    short8 r;
    #pragma unroll
    for (int j = 0; j < 8; j++) r[j] = (short)f2bf(acc[j]);
    *(short8*)&O[(long)node * HD + fl] = r;
  }
}

// ---------------- edge classifier via MFMA + fused log_softmax/NLL ----------------
__global__ __launch_bounds__(256) void k_edge(const ushort_t* __restrict__ H,
                                              const int* __restrict__ row,
                                              const int* __restrict__ col,
                                              const int* __restrict__ label,
                                              const ushort_t* __restrict__ Bp,
                                              const float* __restrict__ bfc,
                                              float* __restrict__ logits,
                                              float* __restrict__ lossb) {
  __shared__ float Ls[4];
  int tid = threadIdx.x;
  int w = tid >> 6, lane = tid & 63;
  int ebase = blockIdx.x * 64 + w * 16;  // 9375*64 = 600000 exactly
  int m = lane & 15, g = lane >> 4;

  short8 bf[8];
  #pragma unroll
  for (int t = 0; t < 8; t++) bf[t] = *(const short8*)&Bp[(t * 64 + lane) * 8];

  int r = row[ebase + m];
  int c = col[ebase + m];
  long br = (long)r * HD, bc = (long)c * HD;
  int ko = g * 8;

  short8 a[8];
  #pragma unroll
  for (int t = 0; t < 4; t++) {
    a[t]     = *(const short8*)&H[br + t * 32 + ko];
    a[4 + t] = *(const short8*)&H[bc + t * 32 + ko];
  }

  f32x4 acc = {0.f, 0.f, 0.f, 0.f};
  #pragma unroll
  for (int t = 0; t < 8; t++)
    acc = __builtin_amdgcn_mfma_f32_16x16x32_bf16(a[t], bf[t], acc, 0, 0, 0);

  // C layout: class n = lane&15 = m, edge = ebase + g*4 + reg
  float bias = (m < NC) ? bfc[m] : 0.f;
  float lp = 0.f;
  #pragma unroll
  for (int reg = 0; reg < 4; reg++) {
    int e = ebase + g * 4 + reg;
    float v = acc[reg] + bias;
    if (m < NC) logits[(long)e * NC + m] = v;
    // log-softmax over the 16 lanes of this group (classes 10..15 masked)
    float mx = (m < NC) ? v : -3e38f;
    #pragma unroll
    for (int off = 1; off < 16; off <<= 1) mx = fmaxf(mx, __shfl_xor(mx, off, 16));
    float ex = (m < NC) ? __expf(v - mx) : 0.f;
    #pragma unroll
    for (int off = 1; off < 16; off <<= 1) ex += __shfl_xor(ex, off, 16);
    int lb = label[e];
    float pl = (m == lb) ? v : 0.f;
    #pragma unroll
    for (int off = 1; off < 16; off <<= 1) pl += __shfl_xor(pl, off, 16);
    lp += pl - mx - __logf(ex);
  }
  float lc = (m == 0) ? lp : 0.f;   // one lane per group contributes
  #pragma unroll
  for (int off = 1; off < 64; off <<= 1) lc += __shfl_xor(lc, off, 64);
  if (lane == 0) Ls[w] = lc;
  __syncthreads();
  if (tid == 0) unsafeAtomicAdd(lossb, Ls[0] + Ls[1] + Ls[2] + Ls[3]);
}

__global__ void k_loss(const float* lossb, float* out) {
  out[0] = -lossb[0] / (float)NE;
}

extern "C" void kernel_launch(void* const* d_in, const int* in_sizes, int n_in,
                              void* d_out, int out_size, void* d_ws, size_t ws_size,
                              hipStream_t stream) {
  const float* features = (const float*)d_in[0];
  const float* W1  = (const float*)d_in[1];
  const float* b1  = (const float*)d_in[2];
  const float* W2  = (const float*)d_in[3];
  const float* b2  = (const float*)d_in[4];
  const float* Wfc = (const float*)d_in[5];
  const float* bfc = (const float*)d_in[6];
  const int* row   = (const int*)d_in[7];
  const int* col   = (const int*)d_in[8];
  const int* label = (const int*)d_in[9];
  float* out = (float*)d_out;

  float* ws = (float*)d_ws;
  size_t o = 0;
  int*   pos    = (int*)(ws + o); o += 50048;
  int*   rowcnt = (int*)(ws + o); o += 50048;
  int*   srcs   = (int*)(ws + o); o += (size_t)NND * CAP;  // 12.8 MB padded buckets
  float* lossb  = ws + o;         o += 16;
  ushort_t* Bp  = (ushort_t*)(ws + o); o += 2048;   // Wfc fragments
  ushort_t* Bw1 = (ushort_t*)(ws + o); o += 8192;   // W1 fragments
  ushort_t* Bw2 = (ushort_t*)(ws + o); o += 8192;
  ushort_t* bufA = (ushort_t*)(ws + o); o += 3200000;
  ushort_t* bufB = (ushort_t*)(ws + o); o += 3200000;

  // init + weight prep
  k_init_prep<<<213, 256, 0, stream>>>(pos, rowcnt, lossb, Wfc, W1, W2, Bp, Bw1, Bw2);
  // conv1 GEMM fused with graph build (gemm hides inside atomic shadow)
  k_mega<<<GEMMB + ATOMB, 256, 0, stream>>>(features, Bw1, b1, bufA, row, col, pos, rowcnt, srcs);
  // conv1 aggregate, conv2 GEMM, conv2 aggregate
  k_aggr<<<6250, 256, 0, stream>>>(bufA, srcs, pos, rowcnt, bufB);
  k_gemm2<<<782, 256, 0, stream>>>(bufB, Bw2, b2, bufA);
  k_aggr<<<6250, 256, 0, stream>>>(bufA, srcs, pos, rowcnt, bufB);
  // edge classifier + fused loss
  k_edge<<<9375, 256, 0, stream>>>(bufB, row, col, label, Bp, bfc, out + 1, lossb);
  k_loss<<<1, 1, 0, stream>>>(lossb, out);
}

// Round 6
// 289.430 us; speedup vs baseline: 3.0102x; 3.0102x over previous
//
#include <hip/hip_runtime.h>
#include <hip/hip_bf16.h>
#include <math.h>

#define NND 50000
#define NE  600000
#define HD  128
#define NC  10
#define CAP 64          // per-node in-edge bucket capacity (Poisson mean 12; P(>=64) ~ 1e-30)
#define GEMMB 782       // gemm blocks in k_mega (782*64 = 50048 rows)
#define ATOMB 1024      // atomic blocks in k_mega
#define LOSSB 2344      // loss blocks (2344*256 >= NE)

typedef unsigned short ushort_t;
typedef __attribute__((ext_vector_type(8))) short short8;
typedef __attribute__((ext_vector_type(4))) float f32x4;

__device__ __forceinline__ float bf2f(unsigned short u) {
  return __uint_as_float(((unsigned int)u) << 16);
}
__device__ __forceinline__ unsigned short f2bf(float f) {
  __hip_bfloat16 h = __float2bfloat16(f);  // RNE
  return *(unsigned short*)&h;
}

// ---------------- init (pos=0, rowcnt=0) + weight fragment prep ----------------
// blocks [0,196): zero arrays; blocks [196,213): pack Wfc/W1/W2 into MFMA B-fragment order.
// B-frag layout (HW-verified R3/R4): Bfrag[(t*64+lane)*8+j] = W[n = nt*16 + (lane&15)][k = t*32 + ((lane>>4)&3)*8 + j]
__global__ void k_init_prep(int* pos, int* rowcnt,
                            const float* __restrict__ Wfc, const float* __restrict__ W1,
                            const float* __restrict__ W2, ushort_t* __restrict__ Bp,
                            ushort_t* __restrict__ Bw1, ushort_t* __restrict__ Bw2) {
  int bb = blockIdx.x, tid = threadIdx.x;
  if (bb < 196) {
    int i = bb * 256 + tid;
    if (i < NND) { pos[i] = 0; rowcnt[i] = 0; }
  } else if (bb == 196) {
    // Wfc: K=256, one 16-padded n-tile
    for (int idx = tid; idx < 8 * 64; idx += 256) {
      int t = idx >> 6, lane = idx & 63;
      int n = lane & 15, q = (lane >> 4) & 3;
      #pragma unroll
      for (int j = 0; j < 8; j++) {
        int k = t * 32 + q * 8 + j;
        float v = (n < NC) ? Wfc[n * 256 + k] : 0.f;
        Bp[idx * 8 + j] = f2bf(v);
      }
    }
  } else {
    const float* W = (bb <= 204) ? W1 : W2;
    ushort_t* B = (bb <= 204) ? Bw1 : Bw2;
    int nt = (bb - 197) & 7;
    for (int idx = tid; idx < 4 * 64; idx += 256) {
      int t = idx >> 6, lane = idx & 63;
      int n = nt * 16 + (lane & 15), q = (lane >> 4) & 3;
      #pragma unroll
      for (int j = 0; j < 8; j++) {
        int k = t * 32 + q * 8 + j;
        B[(nt * 256 + idx) * 8 + j] = f2bf(W[n * HD + k]);
      }
    }
  }
}

// ---------------- shared GEMM body: Y[r][n] = b[n] + sum_k X[r][k]*W[n][k]; 64 rows/block ----------------
template <bool FP32IN>
__device__ __forceinline__ void gemm_body(const void* __restrict__ Xv,
                                          const ushort_t* __restrict__ Bw,
                                          const float* __restrict__ b,
                                          ushort_t* __restrict__ Y,
                                          ushort_t* Bs, int bid, int tid) {
  for (int i = tid; i < 2048; i += 256)
    *(short8*)&Bs[i * 8] = *(const short8*)&Bw[i * 8];
  __syncthreads();
  int w = tid >> 6, lane = tid & 63;
  int m = lane & 15, q = lane >> 4;
  int rowbase = bid * 64 + w * 16;
  int rm = rowbase + m; if (rm >= NND) rm = NND - 1;  // clamp: row m only affects row m outputs
  short8 a[4];
  if (FP32IN) {
    const float* X = (const float*)Xv;
    #pragma unroll
    for (int t = 0; t < 4; t++) {
      const float* p0 = &X[(long)rm * HD + t * 32 + q * 8];
      float4 x0 = *(const float4*)p0;
      float4 x1 = *(const float4*)(p0 + 4);
      short8 av;
      av[0] = (short)f2bf(x0.x); av[1] = (short)f2bf(x0.y);
      av[2] = (short)f2bf(x0.z); av[3] = (short)f2bf(x0.w);
      av[4] = (short)f2bf(x1.x); av[5] = (short)f2bf(x1.y);
      av[6] = (short)f2bf(x1.z); av[7] = (short)f2bf(x1.w);
      a[t] = av;
    }
  } else {
    const ushort_t* X = (const ushort_t*)Xv;
    #pragma unroll
    for (int t = 0; t < 4; t++)
      a[t] = *(const short8*)&X[(long)rm * HD + t * 32 + q * 8];
  }
  #pragma unroll
  for (int nt = 0; nt < 8; nt++) {
    f32x4 acc = {0.f, 0.f, 0.f, 0.f};
    #pragma unroll
    for (int t = 0; t < 4; t++) {
      short8 bf = *(const short8*)&Bs[((nt * 4 + t) * 64 + lane) * 8];
      acc = __builtin_amdgcn_mfma_f32_16x16x32_bf16(a[t], bf, acc, 0, 0, 0);
    }
    float bias = b[nt * 16 + m];
    #pragma unroll
    for (int reg = 0; reg < 4; reg++) {
      int r = rowbase + q * 4 + reg;
      if (r < NND) Y[(long)r * HD + nt * 16 + m] = f2bf(acc[reg] + bias);
    }
  }
}

// ---------------- mega: blocks [0,GEMMB) = conv1 GEMM; rest = graph build (atomics) ----------------
__global__ __launch_bounds__(256) void k_mega(const float* __restrict__ features,
                                              const ushort_t* __restrict__ Bw1,
                                              const float* __restrict__ b1,
                                              ushort_t* __restrict__ Y,
                                              const int* __restrict__ row,
                                              const int* __restrict__ col,
                                              int* pos, int* rowcnt,
                                              int* __restrict__ srcs) {
  __shared__ ushort_t Bs[16384];  // 32 KB (only gemm blocks touch it)
  int tid = threadIdx.x;
  if (blockIdx.x < GEMMB) {
    gemm_body<true>((const void*)features, Bw1, b1, Y, Bs, blockIdx.x, tid);
  } else {
    int idx = (blockIdx.x - GEMMB) * 256 + tid;
    for (int e = idx; e < NE; e += ATOMB * 256) {
      int c = col[e], r = row[e];
      int p = atomicAdd(&pos[c], 1);     // fill slot == running count
      if (p < CAP) srcs[(long)c * CAP + p] = r;
      atomicAdd(&rowcnt[r], 1);          // out-degree histogram
    }
  }
}

// ---------------- conv2 GEMM (bf16 in) ----------------
__global__ __launch_bounds__(256) void k_gemm2(const ushort_t* __restrict__ X,
                                               const ushort_t* __restrict__ Bw,
                                               const float* __restrict__ b,
                                               ushort_t* __restrict__ Y) {
  __shared__ ushort_t Bs[16384];
  gemm_body<false>((const void*)X, Bw, b, Y, Bs, blockIdx.x, threadIdx.x);
}

// ---------------- aggregation: padded buckets, 16B gathers, two neighbors in flight ----------------
// O[i] = dinv[i]^2*H[i] + sum_{e:col=i} dinv[src]*dinv[i]*H[src],  dinv = rsqrt(1+rowcnt)
__global__ __launch_bounds__(256) void k_aggr(const ushort_t* __restrict__ H,
                                              const int* __restrict__ srcs,
                                              const int* __restrict__ pos,
                                              const int* __restrict__ rowcnt,
                                              ushort_t* __restrict__ O) {
  int g = threadIdx.x >> 5, lane = threadIdx.x & 31;
  int half = lane >> 4;            // 0: even neighbor slots, 1: odd slots
  int fl = (lane & 15) * 8;        // feature base (8 bf16 = 16 B per lane)
  int node = blockIdx.x * 8 + g;
  if (node >= NND) return;
  float di = rsqrtf(1.0f + (float)rowcnt[node]);
  short8 hv = *(const short8*)&H[(long)node * HD + fl];
  float acc[8];
  float sw = (half == 0) ? di * di : 0.0f;   // self-loop term only in half 0
  #pragma unroll
  for (int j = 0; j < 8; j++) acc[j] = sw * bf2f((unsigned short)hv[j]);
  int cnt = pos[node]; if (cnt > CAP) cnt = CAP;
  const int* nb = &srcs[(long)node * CAP];
  for (int base = 0; base < cnt; base += 32) {
    int m = cnt - base; if (m > 32) m = 32;
    int sl = 0; float wl = 0.f;
    if (lane < m) { sl = nb[base + lane]; wl = di * rsqrtf(1.0f + (float)rowcnt[sl]); }
    int iters = (m + 1) >> 1;
    for (int u = 0; u < iters; u++) {
      int t = 2 * u + half;                      // t<=m; lane t>=m holds sl=0, wl=0
      int s = __shfl(sl, t & 31, 32);
      float w = __shfl(wl, t & 31, 32);
      short8 hs = *(const short8*)&H[(long)s * HD + fl];
      #pragma unroll
      for (int j = 0; j < 8; j++) acc[j] += w * bf2f((unsigned short)hs[j]);
    }
  }
  // combine halves: lanes 0-15 add lanes 16-31's partials
  #pragma unroll
  for (int j = 0; j < 8; j++) acc[j] += __shfl(acc[j], (lane & 15) + 16, 32);
  if (half == 0) {
    short8 r;
    #pragma unroll
    for (int j = 0; j < 8; j++) r[j] = (short)f2bf(acc[j]);
    *(short8*)&O[(long)node * HD + fl] = r;
  }
}

// ---------------- edge classifier via MFMA: 16 edges x 16 classes per wave (exact R3 form) ----------------
__global__ __launch_bounds__(256) void k_edge(const ushort_t* __restrict__ H,
                                              const int* __restrict__ row,
                                              const int* __restrict__ col,
                                              const ushort_t* __restrict__ Bp,
                                              const float* __restrict__ bfc,
                                              float* __restrict__ logits) {
  int tid = threadIdx.x;
  int w = tid >> 6, lane = tid & 63;
  int ebase = blockIdx.x * 64 + w * 16;  // 9375*64 = 600000 exactly
  int m = lane & 15, g = lane >> 4;

  short8 bf[8];
  #pragma unroll
  for (int t = 0; t < 8; t++) bf[t] = *(const short8*)&Bp[(t * 64 + lane) * 8];

  int r = row[ebase + m];
  int c = col[ebase + m];
  long br = (long)r * HD, bc = (long)c * HD;
  int ko = g * 8;

  short8 a[8];
  #pragma unroll
  for (int t = 0; t < 4; t++) {
    a[t]     = *(const short8*)&H[br + t * 32 + ko];
    a[4 + t] = *(const short8*)&H[bc + t * 32 + ko];
  }

  f32x4 acc = {0.f, 0.f, 0.f, 0.f};
  #pragma unroll
  for (int t = 0; t < 8; t++)
    acc = __builtin_amdgcn_mfma_f32_16x16x32_bf16(a[t], bf[t], acc, 0, 0, 0);

  // C layout: col = lane&15 (class), row = g*4 + reg (edge within tile)
  int n = lane & 15;
  if (n < NC) {
    float bias = bfc[n];
    #pragma unroll
    for (int reg = 0; reg < 4; reg++) {
      int e = ebase + g * 4 + reg;
      logits[(long)e * NC + n] = acc[reg] + bias;
    }
  }
}

// ---------------- loss: streaming log_softmax + NLL; one plain-store partial per block ----------------
__global__ __launch_bounds__(256) void k_loss2(const float* __restrict__ logits,
                                               const int* __restrict__ label,
                                               float* __restrict__ partial) {
  __shared__ float Ls[4];
  int tid = threadIdx.x;
  int e = blockIdx.x * 256 + tid;
  float lp = 0.f;
  if (e < NE) {
    const float* q = logits + (long)e * NC;
    float p[NC];
    #pragma unroll
    for (int i = 0; i < 5; i++) {
      float2 v = *(const float2*)&q[i * 2];
      p[i * 2] = v.x; p[i * 2 + 1] = v.y;
    }
    float mx = p[0];
    #pragma unroll
    for (int cc = 1; cc < NC; cc++) mx = fmaxf(mx, p[cc]);
    float se = 0.f;
    #pragma unroll
    for (int cc = 0; cc < NC; cc++) se += __expf(p[cc] - mx);
    int lb = label[e];
    float plb = p[0];
    #pragma unroll
    for (int cc = 1; cc < NC; cc++) plb = (cc == lb) ? p[cc] : plb;
    lp = plb - mx - __logf(se);
  }
  #pragma unroll
  for (int off = 32; off > 0; off >>= 1) lp += __shfl_xor(lp, off, 64);
  if ((tid & 63) == 0) Ls[tid >> 6] = lp;
  __syncthreads();
  if (tid == 0) partial[blockIdx.x] = Ls[0] + Ls[1] + Ls[2] + Ls[3];
}

// ---------------- final: reduce partials, write loss ----------------
__global__ __launch_bounds__(256) void k_loss(const float* __restrict__ partial,
                                              float* __restrict__ out) {
  __shared__ float Ls[4];
  int tid = threadIdx.x;
  float s = 0.f;
  for (int i = tid; i < LOSSB; i += 256) s += partial[i];
  #pragma unroll
  for (int off = 32; off > 0; off >>= 1) s += __shfl_xor(s, off, 64);
  if ((tid & 63) == 0) Ls[tid >> 6] = s;
  __syncthreads();
  if (tid == 0) out[0] = -(Ls[0] + Ls[1] + Ls[2] + Ls[3]) / (float)NE;
}

extern "C" void kernel_launch(void* const* d_in, const int* in_sizes, int n_in,
                              void* d_out, int out_size, void* d_ws, size_t ws_size,
                              hipStream_t stream) {
  const float* features = (const float*)d_in[0];
  const float* W1  = (const float*)d_in[1];
  const float* b1  = (const float*)d_in[2];
  const float* W2  = (const float*)d_in[3];
  const float* b2  = (const float*)d_in[4];
  const float* Wfc = (const float*)d_in[5];
  const float* bfc = (const float*)d_in[6];
  const int* row   = (const int*)d_in[7];
  const int* col   = (const int*)d_in[8];
  const int* label = (const int*)d_in[9];
  float* out = (float*)d_out;

  float* ws = (float*)d_ws;
  size_t o = 0;
  int*   pos     = (int*)(ws + o); o += 50048;
  int*   rowcnt  = (int*)(ws + o); o += 50048;
  int*   srcs    = (int*)(ws + o); o += (size_t)NND * CAP;  // 12.8 MB padded buckets
  float* partial = ws + o;         o += LOSSB + 8;
  ushort_t* Bp  = (ushort_t*)(ws + o); o += 2048;   // Wfc fragments
  ushort_t* Bw1 = (ushort_t*)(ws + o); o += 8192;   // W1 fragments
  ushort_t* Bw2 = (ushort_t*)(ws + o); o += 8192;
  ushort_t* bufA = (ushort_t*)(ws + o); o += 3200000;
  ushort_t* bufB = (ushort_t*)(ws + o); o += 3200000;

  // init + weight prep
  k_init_prep<<<213, 256, 0, stream>>>(pos, rowcnt, Wfc, W1, W2, Bp, Bw1, Bw2);
  // conv1 GEMM fused with graph build (gemm hides inside atomic shadow)
  k_mega<<<GEMMB + ATOMB, 256, 0, stream>>>(features, Bw1, b1, bufA, row, col, pos, rowcnt, srcs);
  // conv1 aggregate, conv2 GEMM, conv2 aggregate
  k_aggr<<<6250, 256, 0, stream>>>(bufA, srcs, pos, rowcnt, bufB);
  k_gemm2<<<782, 256, 0, stream>>>(bufB, Bw2, b2, bufA);
  k_aggr<<<6250, 256, 0, stream>>>(bufA, srcs, pos, rowcnt, bufB);
  // edge classifier + loss
  k_edge<<<9375, 256, 0, stream>>>(bufB, row, col, Bp, bfc, out + 1);
  k_loss2<<<LOSSB, 256, 0, stream>>>(out + 1, label, partial);
  k_loss<<<1, 256, 0, stream>>>(partial, out);
}